// Round 4
// baseline (59.724 us; speedup 1.0000x reference)
//
#include <hip/hip_runtime.h>
#include <math.h>

#define BB 32
#define NN 4096
#define DD 512
#define ROWS_PER_WAVE 16   // 8192 waves * 16 rows = 131072 = B*N
#define WAVES_TOTAL (BB * NN / ROWS_PER_WAVE)       // 8192
#define WAVES_PER_BATCH (NN / ROWS_PER_WAVE)        // 256

typedef float v4f __attribute__((ext_vector_type(4)));

// DPP sum within each 32-lane half; valid result lands in lanes 31 and 63.
// row_shr:1/2/4/8 within rows of 16, then row_bcast15 merges the row pair.
__device__ __forceinline__ float dpp_reduce_half32(float v) {
#define DPP_ADD(ctrl) \
    v += __int_as_float(__builtin_amdgcn_update_dpp( \
        0, __float_as_int(v), ctrl, 0xF, 0xF, true))
    DPP_ADD(0x111);  // row_shr:1
    DPP_ADD(0x112);  // row_shr:2
    DPP_ADD(0x114);  // row_shr:4
    DPP_ADD(0x118);  // row_shr:8  -> lane {15,31,47,63} hold row-of-16 sums
    DPP_ADD(0x142);  // row_bcast15 -> lane 31 = sum(0..31), lane 63 = sum(32..63)
#undef DPP_ADD
    return v;
}

__device__ __forceinline__ float dot4(v4f a, v4f b) {
    return a.x * b.x + a.y * b.y + a.z * b.z + a.w * b.w;
}

// Each wave owns 16 consecutive rows of one batch; two rows per iteration
// (half-wave per row, 64 B/lane, per-instruction contiguous loads).
// Passing rows go to the wave's PRIVATE slot range list[wg*16 ..]; the count
// is written unconditionally -> no atomics, no pre-zeroing, no memset kernel.
__global__ __launch_bounds__(256) void sim_pass1_kernel(
    const float* __restrict__ q, const float* __restrict__ key,
    const unsigned char* __restrict__ mask,
    int* __restrict__ wcount, int2* __restrict__ list)
{
    const int lane = threadIdx.x & 63;
    const int half = lane >> 5;
    const int l32  = lane & 31;
    const int wave = threadIdx.x >> 6;
    const int wg   = blockIdx.x * (blockDim.x >> 6) + wave;   // 0..8191
    const int r0   = wg * ROWS_PER_WAVE;                      // chunk stays in one batch
    const int b    = r0 >> 12;                                // N = 4096

    // Load q once per wave (both halves load identical data -> each half's
    // reduce yields the full ||q||^2 in its leader lane).
    const v4f* qr = reinterpret_cast<const v4f*>(q + (size_t)b * DD);
    v4f qv0 = qr[l32 + 0];
    v4f qv1 = qr[l32 + 32];
    v4f qv2 = qr[l32 + 64];
    v4f qv3 = qr[l32 + 96];
    float qq = dot4(qv0, qv0) + dot4(qv1, qv1) + dot4(qv2, qv2) + dot4(qv3, qv3);
    qq = dpp_reduce_half32(qq);
    const float qn = sqrtf(qq);          // valid in lanes 31, 63

    const bool leader = (l32 == 31);     // lanes 31 and 63
    int base = 0;                        // uniform running slot offset

#pragma unroll 2
    for (int i = 0; i < ROWS_PER_WAVE / 2; ++i) {
        const int row = r0 + 2 * i + half;
        const v4f* kr = reinterpret_cast<const v4f*>(key + (size_t)row * DD);
        v4f k0 = __builtin_nontemporal_load(&kr[l32 + 0]);
        v4f k1 = __builtin_nontemporal_load(&kr[l32 + 32]);
        v4f k2 = __builtin_nontemporal_load(&kr[l32 + 64]);
        v4f k3 = __builtin_nontemporal_load(&kr[l32 + 96]);

        float dot = dot4(k0, qv0) + dot4(k1, qv1) + dot4(k2, qv2) + dot4(k3, qv3);
        float kk  = dot4(k0, k0) + dot4(k1, k1) + dot4(k2, k2) + dot4(k3, k3);

        dot = dpp_reduce_half32(dot);
        kk  = dpp_reduce_half32(kk);

        bool pass = false;
        float attn = 0.0f;
        if (leader) {
            float denom = fmaxf(qn * sqrtf(kk), 1e-8f);
            attn = dot / denom;
            pass = (attn >= 0.9f) && (mask[row] == 0);
        }
        unsigned long long bal = __ballot(pass);
        int lo = (int)((bal >> 31) & 1ull);   // lane 31 (row 2i) passed?
        int hi = (int)((bal >> 63) & 1ull);   // lane 63 (row 2i+1) passed?
        if (pass) {
            int slot = base + ((lane == 63) ? lo : 0);
            list[(size_t)wg * ROWS_PER_WAVE + slot] =
                make_int2(row & (NN - 1), __float_as_int(attn));
        }
        base += lo + hi;
    }

    if (lane == 0) wcount[wg] = base;
}

// One block per batch, one thread per output element: scan the batch's 256
// per-wave counts (uniform -> broadcast loads), gather selected value rows.
__global__ __launch_bounds__(512) void sim_pass2_kernel(
    const float* __restrict__ value, const int* __restrict__ wcount,
    const int2* __restrict__ list, float* __restrict__ out)
{
    const int b = blockIdx.x;
    const int d = threadIdx.x;
    const int wbase = b * WAVES_PER_BATCH;
    float asum = 0.0f;
    float acc  = 0.0f;
    for (int w0 = 0; w0 < WAVES_PER_BATCH; w0 += 4) {
        int4 c4 = *reinterpret_cast<const int4*>(&wcount[wbase + w0]);
#pragma unroll
        for (int k = 0; k < 4; ++k) {
            int c = (k == 0) ? c4.x : (k == 1) ? c4.y : (k == 2) ? c4.z : c4.w;
            if (c == 0) continue;
            const int2* lw = &list[(size_t)(wbase + w0 + k) * ROWS_PER_WAVE];
            for (int j = 0; j < c; ++j) {
                int2 e = lw[j];
                float a = __int_as_float(e.y);
                asum += a;
                acc  += a * value[((size_t)b * NN + e.x) * DD + d];
            }
        }
    }
    out[(size_t)b * DD + d] = acc / (asum + 1e-8f);
}

extern "C" void kernel_launch(void* const* d_in, const int* in_sizes, int n_in,
                              void* d_out, int out_size, void* d_ws, size_t ws_size,
                              hipStream_t stream) {
    const float* query = (const float*)d_in[0];                // [B, D]
    const float* key   = (const float*)d_in[1];                // [B, N, D]
    const float* value = (const float*)d_in[2];                // [B, N, D]
    const unsigned char* mask = (const unsigned char*)d_in[3]; // [B, N] bool
    float* out = (float*)d_out;                                // [B, D]

    char* ws = (char*)d_ws;
    int*  wcount = (int*)(ws);                         // 8192 ints = 32 KiB
    int2* list   = (int2*)(ws + WAVES_TOTAL * 4);      // 8192*16 int2 = 1 MiB

    sim_pass1_kernel<<<WAVES_TOTAL / 4, 256, 0, stream>>>(query, key, mask,
                                                          wcount, list);
    sim_pass2_kernel<<<BB, DD, 0, stream>>>(value, wcount, list, out);
}

// Round 5
// 59.620 us; speedup vs baseline: 1.0017x; 1.0017x over previous
//
#include <hip/hip_runtime.h>
#include <math.h>

#define BB 32
#define NN 4096
#define DD 512
#define ROWS_PER_WAVE 16   // 8192 waves * 16 rows = 131072 = B*N
#define WAVES_TOTAL (BB * NN / ROWS_PER_WAVE)       // 8192
#define WAVES_PER_BATCH (NN / ROWS_PER_WAVE)        // 256

typedef float v4f __attribute__((ext_vector_type(4)));

// 5-stage butterfly over a 32-lane half-wave; all 32 lanes end with the sum.
__device__ __forceinline__ float half_reduce_add(float v) {
    v += __shfl_xor(v, 16, 64);
    v += __shfl_xor(v, 8, 64);
    v += __shfl_xor(v, 4, 64);
    v += __shfl_xor(v, 2, 64);
    v += __shfl_xor(v, 1, 64);
    return v;
}

__device__ __forceinline__ float dot4(v4f a, v4f b) {
    return a.x * b.x + a.y * b.y + a.z * b.z + a.w * b.w;
}

// Each wave owns 16 consecutive rows of one batch; two rows per iteration
// (half-wave per row, 64 B/lane, per-instruction contiguous loads).
// Passing rows go to the wave's PRIVATE slot range list[wg*16 ..]; the count
// is written unconditionally -> no atomics, no pre-zeroing, no memset kernel.
__global__ __launch_bounds__(256) void sim_pass1_kernel(
    const float* __restrict__ q, const float* __restrict__ key,
    const unsigned char* __restrict__ mask,
    int* __restrict__ wcount, int2* __restrict__ list)
{
    const int lane = threadIdx.x & 63;
    const int half = lane >> 5;
    const int l32  = lane & 31;
    const int wave = threadIdx.x >> 6;
    const int wg   = blockIdx.x * (blockDim.x >> 6) + wave;   // 0..8191
    const int r0   = wg * ROWS_PER_WAVE;                      // chunk stays in one batch
    const int b    = r0 >> 12;                                // N = 4096

    // Load q once per wave (both halves load identical data).
    const v4f* qr = reinterpret_cast<const v4f*>(q + (size_t)b * DD);
    v4f qv0 = qr[l32 + 0];
    v4f qv1 = qr[l32 + 32];
    v4f qv2 = qr[l32 + 64];
    v4f qv3 = qr[l32 + 96];
    float qq = dot4(qv0, qv0) + dot4(qv1, qv1) + dot4(qv2, qv2) + dot4(qv3, qv3);
    qq = half_reduce_add(qq);
    const float qn = sqrtf(qq);

    const bool leader = (l32 == 0);      // lanes 0 and 32
    int base = 0;                        // uniform running slot offset

#pragma unroll 2
    for (int i = 0; i < ROWS_PER_WAVE / 2; ++i) {
        const int row = r0 + 2 * i + half;
        const v4f* kr = reinterpret_cast<const v4f*>(key + (size_t)row * DD);
        v4f k0 = __builtin_nontemporal_load(&kr[l32 + 0]);
        v4f k1 = __builtin_nontemporal_load(&kr[l32 + 32]);
        v4f k2 = __builtin_nontemporal_load(&kr[l32 + 64]);
        v4f k3 = __builtin_nontemporal_load(&kr[l32 + 96]);

        float dot = dot4(k0, qv0) + dot4(k1, qv1) + dot4(k2, qv2) + dot4(k3, qv3);
        float kk  = dot4(k0, k0) + dot4(k1, k1) + dot4(k2, k2) + dot4(k3, k3);

        dot = half_reduce_add(dot);
        kk  = half_reduce_add(kk);

        bool pass = false;
        float attn = 0.0f;
        if (leader) {
            float denom = fmaxf(qn * sqrtf(kk), 1e-8f);
            attn = dot / denom;
            pass = (attn >= 0.9f) && (mask[row] == 0);
        }
        unsigned long long bal = __ballot(pass);
        int lo = (int)(bal & 1ull);            // lane 0  (row 2i) passed?
        int hi = (int)((bal >> 32) & 1ull);    // lane 32 (row 2i+1) passed?
        if (pass) {
            int slot = base + ((lane == 32) ? lo : 0);
            list[(size_t)wg * ROWS_PER_WAVE + slot] =
                make_int2(row & (NN - 1), __float_as_int(attn));
        }
        base += lo + hi;
    }

    if (lane == 0) wcount[wg] = base;
}

// One block per batch, one thread per output element: scan the batch's 256
// per-wave counts (uniform -> broadcast loads), gather selected value rows.
__global__ __launch_bounds__(512) void sim_pass2_kernel(
    const float* __restrict__ value, const int* __restrict__ wcount,
    const int2* __restrict__ list, float* __restrict__ out)
{
    const int b = blockIdx.x;
    const int d = threadIdx.x;
    const int wbase = b * WAVES_PER_BATCH;
    float asum = 0.0f;
    float acc  = 0.0f;
    for (int w0 = 0; w0 < WAVES_PER_BATCH; w0 += 4) {
        int4 c4 = *reinterpret_cast<const int4*>(&wcount[wbase + w0]);
#pragma unroll
        for (int k = 0; k < 4; ++k) {
            int c = (k == 0) ? c4.x : (k == 1) ? c4.y : (k == 2) ? c4.z : c4.w;
            if (c == 0) continue;
            const int2* lw = &list[(size_t)(wbase + w0 + k) * ROWS_PER_WAVE];
            for (int j = 0; j < c; ++j) {
                int2 e = lw[j];
                float a = __int_as_float(e.y);
                asum += a;
                acc  += a * value[((size_t)b * NN + e.x) * DD + d];
            }
        }
    }
    out[(size_t)b * DD + d] = acc / (asum + 1e-8f);
}

extern "C" void kernel_launch(void* const* d_in, const int* in_sizes, int n_in,
                              void* d_out, int out_size, void* d_ws, size_t ws_size,
                              hipStream_t stream) {
    const float* query = (const float*)d_in[0];                // [B, D]
    const float* key   = (const float*)d_in[1];                // [B, N, D]
    const float* value = (const float*)d_in[2];                // [B, N, D]
    const unsigned char* mask = (const unsigned char*)d_in[3]; // [B, N] bool
    float* out = (float*)d_out;                                // [B, D]

    char* ws = (char*)d_ws;
    int*  wcount = (int*)(ws);                         // 8192 ints = 32 KiB
    int2* list   = (int2*)(ws + WAVES_TOTAL * 4);      // 8192*16 int2 = 1 MiB

    sim_pass1_kernel<<<WAVES_TOTAL / 4, 256, 0, stream>>>(query, key, mask,
                                                          wcount, list);
    sim_pass2_kernel<<<BB, DD, 0, stream>>>(value, wcount, list, out);
}

// Round 6
// 48.734 us; speedup vs baseline: 1.2255x; 1.2234x over previous
//
#include <hip/hip_runtime.h>
#include <math.h>

#define BB 32
#define NN 4096
#define DD 512
#define ROWS_PER_WAVE 16   // 8192 waves * 16 rows = 131072 = B*N
#define WAVES_TOTAL (BB * NN / ROWS_PER_WAVE)       // 8192
#define WAVES_PER_BATCH (NN / ROWS_PER_WAVE)        // 256

typedef float v4f __attribute__((ext_vector_type(4)));

// 5-stage butterfly over a 32-lane half-wave; all 32 lanes end with the sum.
__device__ __forceinline__ float half_reduce_add(float v) {
    v += __shfl_xor(v, 16, 64);
    v += __shfl_xor(v, 8, 64);
    v += __shfl_xor(v, 4, 64);
    v += __shfl_xor(v, 2, 64);
    v += __shfl_xor(v, 1, 64);
    return v;
}

__device__ __forceinline__ float dot4(v4f a, v4f b) {
    return a.x * b.x + a.y * b.y + a.z * b.z + a.w * b.w;
}

// Each wave owns 16 consecutive rows of one batch; two rows per iteration
// (half-wave per row, 64 B/lane, per-instruction contiguous loads).
// Passing rows go to the wave's PRIVATE slot range list[wg*16 ..]; the count
// is written unconditionally -> no atomics, no pre-zeroing, no memset kernel.
__global__ __launch_bounds__(256) void sim_pass1_kernel(
    const float* __restrict__ q, const float* __restrict__ key,
    const unsigned char* __restrict__ mask,
    int* __restrict__ wcount, int2* __restrict__ list)
{
    const int lane = threadIdx.x & 63;
    const int half = lane >> 5;
    const int l32  = lane & 31;
    const int wave = threadIdx.x >> 6;
    const int wg   = blockIdx.x * (blockDim.x >> 6) + wave;   // 0..8191
    const int r0   = wg * ROWS_PER_WAVE;                      // chunk stays in one batch
    const int b    = r0 >> 12;                                // N = 4096

    // Load q once per wave (both halves load identical data).
    const v4f* qr = reinterpret_cast<const v4f*>(q + (size_t)b * DD);
    v4f qv0 = qr[l32 + 0];
    v4f qv1 = qr[l32 + 32];
    v4f qv2 = qr[l32 + 64];
    v4f qv3 = qr[l32 + 96];
    float qq = dot4(qv0, qv0) + dot4(qv1, qv1) + dot4(qv2, qv2) + dot4(qv3, qv3);
    qq = half_reduce_add(qq);
    const float qn = sqrtf(qq);

    const bool leader = (l32 == 0);      // lanes 0 and 32
    int base = 0;                        // uniform running slot offset

#pragma unroll 2
    for (int i = 0; i < ROWS_PER_WAVE / 2; ++i) {
        const int row = r0 + 2 * i + half;
        const v4f* kr = reinterpret_cast<const v4f*>(key + (size_t)row * DD);
        v4f k0 = __builtin_nontemporal_load(&kr[l32 + 0]);
        v4f k1 = __builtin_nontemporal_load(&kr[l32 + 32]);
        v4f k2 = __builtin_nontemporal_load(&kr[l32 + 64]);
        v4f k3 = __builtin_nontemporal_load(&kr[l32 + 96]);

        float dot = dot4(k0, qv0) + dot4(k1, qv1) + dot4(k2, qv2) + dot4(k3, qv3);
        float kk  = dot4(k0, k0) + dot4(k1, k1) + dot4(k2, k2) + dot4(k3, k3);

        dot = half_reduce_add(dot);
        kk  = half_reduce_add(kk);

        bool pass = false;
        float attn = 0.0f;
        if (leader) {
            float denom = fmaxf(qn * sqrtf(kk), 1e-8f);
            attn = dot / denom;
            pass = (attn >= 0.9f) && (mask[row] == 0);
        }
        unsigned long long bal = __ballot(pass);
        int lo = (int)(bal & 1ull);            // lane 0  (row 2i) passed?
        int hi = (int)((bal >> 32) & 1ull);    // lane 32 (row 2i+1) passed?
        if (pass) {
            int slot = base + ((lane == 32) ? lo : 0);
            list[(size_t)wg * ROWS_PER_WAVE + slot] =
                make_int2(row & (NN - 1), __float_as_int(attn));
        }
        base += lo + hi;
    }

    if (lane == 0) wcount[wg] = base;
}

// One block per batch. Parallel compaction: threads 0..255 load the 256
// per-wave counts (one coalesced load), LDS+shfl prefix-sum, copy private
// entries into a compacted LDS array; then all 512 threads gather value rows.
__global__ __launch_bounds__(512) void sim_pass2_kernel(
    const float* __restrict__ value, const int* __restrict__ wcount,
    const int2* __restrict__ list, float* __restrict__ out)
{
    __shared__ int  s_wsum[4];
    __shared__ int  s_total;
    __shared__ int2 s_ent[NN];     // worst-case all rows pass (32 KiB)

    const int b = blockIdx.x;
    const int t = threadIdx.x;
    const int wbase = b * WAVES_PER_BATCH;

    int c = (t < WAVES_PER_BATCH) ? wcount[wbase + t] : 0;

    // intra-wave inclusive prefix sum
    int x = c;
    for (int d = 1; d < 64; d <<= 1) {
        int y = __shfl_up(x, d, 64);
        if ((t & 63) >= d) x += y;
    }
    if (t < WAVES_PER_BATCH && (t & 63) == 63) s_wsum[t >> 6] = x;
    __syncthreads();

    if (t < WAVES_PER_BATCH) {
        int waveoff = 0;
        for (int w = 0; w < (t >> 6); ++w) waveoff += s_wsum[w];
        int excl = waveoff + x - c;            // exclusive prefix
        const int2* lw = &list[(size_t)(wbase + t) * ROWS_PER_WAVE];
        for (int j = 0; j < c; ++j) s_ent[excl + j] = lw[j];
        if (t == WAVES_PER_BATCH - 1) s_total = excl + c;
    }
    __syncthreads();

    const int total = s_total;
    float asum = 0.0f;
    float acc  = 0.0f;
    for (int j = 0; j < total; ++j) {
        int2 e = s_ent[j];                     // LDS broadcast
        float a = __int_as_float(e.y);
        asum += a;
        acc  += a * value[((size_t)b * NN + e.x) * DD + t];
    }
    out[(size_t)b * DD + t] = acc / (asum + 1e-8f);
}

extern "C" void kernel_launch(void* const* d_in, const int* in_sizes, int n_in,
                              void* d_out, int out_size, void* d_ws, size_t ws_size,
                              hipStream_t stream) {
    const float* query = (const float*)d_in[0];                // [B, D]
    const float* key   = (const float*)d_in[1];                // [B, N, D]
    const float* value = (const float*)d_in[2];                // [B, N, D]
    const unsigned char* mask = (const unsigned char*)d_in[3]; // [B, N] bool
    float* out = (float*)d_out;                                // [B, D]

    char* ws = (char*)d_ws;
    int*  wcount = (int*)(ws);                         // 8192 ints = 32 KiB
    int2* list   = (int2*)(ws + WAVES_TOTAL * 4);      // 8192*16 int2 = 1 MiB

    sim_pass1_kernel<<<WAVES_TOTAL / 4, 256, 0, stream>>>(query, key, mask,
                                                          wcount, list);
    sim_pass2_kernel<<<BB, DD, 0, stream>>>(value, wcount, list, out);
}

// Round 7
// 47.094 us; speedup vs baseline: 1.2682x; 1.0348x over previous
//
#include <hip/hip_runtime.h>
#include <math.h>

#define BB 32
#define NN 4096
#define DD 512
#define ROWS_PER_WAVE 16   // 8192 waves * 16 rows = 131072 = B*N
#define WAVES_TOTAL (BB * NN / ROWS_PER_WAVE)       // 8192
#define WAVES_PER_BATCH (NN / ROWS_PER_WAVE)        // 256

typedef float v4f __attribute__((ext_vector_type(4)));

// 5-stage butterfly over a 32-lane half-wave; all 32 lanes end with the sum.
__device__ __forceinline__ float half_reduce_add(float v) {
    v += __shfl_xor(v, 16, 64);
    v += __shfl_xor(v, 8, 64);
    v += __shfl_xor(v, 4, 64);
    v += __shfl_xor(v, 2, 64);
    v += __shfl_xor(v, 1, 64);
    return v;
}

__device__ __forceinline__ float dot4(v4f a, v4f b) {
    return a.x * b.x + a.y * b.y + a.z * b.z + a.w * b.w;
}

// Batch b is owned by 256 waves. At iteration i those waves read the
// CONTIGUOUS row front [512*i, 512*i+512) of that batch (2 rows per wave,
// half-wave per row, 64 B/lane) -> ~32 large sequential DRAM streams
// instead of 8192 scattered ones. Passing rows go to the wave's PRIVATE
// slot range; count written unconditionally -> no atomics, no memset.
__global__ __launch_bounds__(256) void sim_pass1_kernel(
    const float* __restrict__ q, const float* __restrict__ key,
    const unsigned char* __restrict__ mask,
    int* __restrict__ wcount, int2* __restrict__ list)
{
    const int lane = threadIdx.x & 63;
    const int half = lane >> 5;
    const int l32  = lane & 31;
    const int wave = threadIdx.x >> 6;
    const int wg   = blockIdx.x * (blockDim.x >> 6) + wave;   // 0..8191
    const int b    = wg >> 8;                                 // 256 waves/batch
    const int w    = wg & 255;                                // wave within batch

    // Load q once per wave (both halves load identical data).
    const v4f* qr = reinterpret_cast<const v4f*>(q + (size_t)b * DD);
    v4f qv0 = qr[l32 + 0];
    v4f qv1 = qr[l32 + 32];
    v4f qv2 = qr[l32 + 64];
    v4f qv3 = qr[l32 + 96];
    float qq = dot4(qv0, qv0) + dot4(qv1, qv1) + dot4(qv2, qv2) + dot4(qv3, qv3);
    qq = half_reduce_add(qq);
    const float qn = sqrtf(qq);

    const bool leader = (l32 == 0);      // lanes 0 and 32
    int base = 0;                        // uniform running slot offset

#pragma unroll 2
    for (int i = 0; i < ROWS_PER_WAVE / 2; ++i) {
        const int n = 512 * i + 2 * w + half;        // row within batch
        const size_t row = (size_t)b * NN + n;
        const v4f* kr = reinterpret_cast<const v4f*>(key + row * DD);
        v4f k0 = __builtin_nontemporal_load(&kr[l32 + 0]);
        v4f k1 = __builtin_nontemporal_load(&kr[l32 + 32]);
        v4f k2 = __builtin_nontemporal_load(&kr[l32 + 64]);
        v4f k3 = __builtin_nontemporal_load(&kr[l32 + 96]);

        float dot = dot4(k0, qv0) + dot4(k1, qv1) + dot4(k2, qv2) + dot4(k3, qv3);
        float kk  = dot4(k0, k0) + dot4(k1, k1) + dot4(k2, k2) + dot4(k3, k3);

        dot = half_reduce_add(dot);
        kk  = half_reduce_add(kk);

        bool pass = false;
        float attn = 0.0f;
        if (leader) {
            float denom = fmaxf(qn * sqrtf(kk), 1e-8f);
            attn = dot / denom;
            pass = (attn >= 0.9f) && (mask[row] == 0);
        }
        unsigned long long bal = __ballot(pass);
        int lo = (int)(bal & 1ull);            // lane 0  (row n, half 0) passed?
        int hi = (int)((bal >> 32) & 1ull);    // lane 32 (row n+1, half 1) passed?
        if (pass) {
            int slot = base + ((lane == 32) ? lo : 0);
            list[(size_t)wg * ROWS_PER_WAVE + slot] =
                make_int2(n, __float_as_int(attn));
        }
        base += lo + hi;
    }

    if (lane == 0) wcount[wg] = base;
}

// One block per batch. Parallel compaction: threads 0..255 load the 256
// per-wave counts (one coalesced load), LDS+shfl prefix-sum, copy private
// entries into a compacted LDS array; then all 512 threads gather value rows.
__global__ __launch_bounds__(512) void sim_pass2_kernel(
    const float* __restrict__ value, const int* __restrict__ wcount,
    const int2* __restrict__ list, float* __restrict__ out)
{
    __shared__ int  s_wsum[4];
    __shared__ int  s_total;
    __shared__ int2 s_ent[NN];     // worst-case all rows pass (32 KiB)

    const int b = blockIdx.x;
    const int t = threadIdx.x;
    const int wbase = b * WAVES_PER_BATCH;

    int c = (t < WAVES_PER_BATCH) ? wcount[wbase + t] : 0;

    // intra-wave inclusive prefix sum
    int x = c;
    for (int d = 1; d < 64; d <<= 1) {
        int y = __shfl_up(x, d, 64);
        if ((t & 63) >= d) x += y;
    }
    if (t < WAVES_PER_BATCH && (t & 63) == 63) s_wsum[t >> 6] = x;
    __syncthreads();

    if (t < WAVES_PER_BATCH) {
        int waveoff = 0;
        for (int w = 0; w < (t >> 6); ++w) waveoff += s_wsum[w];
        int excl = waveoff + x - c;            // exclusive prefix
        const int2* lw = &list[(size_t)(wbase + t) * ROWS_PER_WAVE];
        for (int j = 0; j < c; ++j) s_ent[excl + j] = lw[j];
        if (t == WAVES_PER_BATCH - 1) s_total = excl + c;
    }
    __syncthreads();

    const int total = s_total;
    float asum = 0.0f;
    float acc  = 0.0f;
    for (int j = 0; j < total; ++j) {
        int2 e = s_ent[j];                     // LDS broadcast
        float a = __int_as_float(e.y);
        asum += a;
        acc  += a * value[((size_t)b * NN + e.x) * DD + t];
    }
    out[(size_t)b * DD + t] = acc / (asum + 1e-8f);
}

extern "C" void kernel_launch(void* const* d_in, const int* in_sizes, int n_in,
                              void* d_out, int out_size, void* d_ws, size_t ws_size,
                              hipStream_t stream) {
    const float* query = (const float*)d_in[0];                // [B, D]
    const float* key   = (const float*)d_in[1];                // [B, N, D]
    const float* value = (const float*)d_in[2];                // [B, N, D]
    const unsigned char* mask = (const unsigned char*)d_in[3]; // [B, N] bool
    float* out = (float*)d_out;                                // [B, D]

    char* ws = (char*)d_ws;
    int*  wcount = (int*)(ws);                         // 8192 ints = 32 KiB
    int2* list   = (int2*)(ws + WAVES_TOTAL * 4);      // 8192*16 int2 = 1 MiB

    sim_pass1_kernel<<<WAVES_TOTAL / 4, 256, 0, stream>>>(query, key, mask,
                                                          wcount, list);
    sim_pass2_kernel<<<BB, DD, 0, stream>>>(value, wcount, list, out);
}